// Round 3
// baseline (356.378 us; speedup 1.0000x reference)
//
#include <hip/hip_runtime.h>
#include <hip/hip_bf16.h>

typedef __attribute__((ext_vector_type(4))) float f32x4;
typedef __attribute__((ext_vector_type(8))) short s16x8;
typedef unsigned short u16;
typedef unsigned int u32;

#define DEV __device__ __forceinline__

DEV u16 f2bf(float f) {
  union { float f; u32 u; } v; v.f = f;
  u32 r = v.u + 0x7fffu + ((v.u >> 16) & 1u);
  return (u16)(r >> 16);
}

#define MFMA16(a, b, c) __builtin_amdgcn_mfma_f32_16x16x32_bf16((a), (b), (c), 0, 0, 0)
#define GLD16(g, l) __builtin_amdgcn_global_load_lds((const __attribute__((address_space(1))) u32*)(g), (__attribute__((address_space(3))) u32*)(l), 16, 0, 0)

#define QSCALE 0.10206207261596577f  // 96^-0.5

// ---------------------------------------------------------------------------
// Fused prep kernel.
//  blocks [0, 2304):  transpose-cast fp32 [768][ncols] -> bf16 [ncols][768]
//                     (qkv weights with Q-scale folded, proj weights)
//  blocks [2304, 3328): patch embed conv + LayerNorm + pos -> x0 fp32 + bf16
__global__ __launch_bounds__(256) void prep_k(
    const float* __restrict__ qw, const float* __restrict__ kvw,
    const float* __restrict__ pw, u16* __restrict__ wqkvT, u16* __restrict__ pwT,
    const float* __restrict__ sam, const float* __restrict__ cw,
    const float* __restrict__ cb, const float* __restrict__ g,
    const float* __restrict__ bb, const float* __restrict__ pos,
    float* __restrict__ x0f, u16* __restrict__ x0b) {
  __shared__ float tb[32][33];
  __shared__ float pix[4][64];
  __shared__ float red[2][4][4];
  int bid = blockIdx.x;
  if (bid < 2304) {
    // ---- weight transpose-cast role ----
    int ct = bid / 24, kt = (bid % 24) * 32;
    const float* src;
    u16* dst;
    int ncols, tn, dstbase;
    float scale = 1.0f;
    if (ct < 24) {
      src = qw; ncols = 768; tn = ct * 32; dst = wqkvT; dstbase = tn; scale = QSCALE;
    } else if (ct < 72) {
      src = kvw; ncols = 1536; tn = (ct - 24) * 32; dst = wqkvT; dstbase = 768 + tn;
    } else {
      src = pw; ncols = 768; tn = (ct - 72) * 32; dst = pwT; dstbase = tn;
    }
    int tx = threadIdx.x & 31, ty = threadIdx.x >> 5;
#pragma unroll
    for (int i = 0; i < 4; i++)
      tb[ty + i * 8][tx] = src[(size_t)(kt + ty + i * 8) * ncols + tn + tx];
    __syncthreads();
#pragma unroll
    for (int i = 0; i < 4; i++)
      dst[(size_t)(dstbase + ty + i * 8) * 768 + kt + tx] = f2bf(tb[tx][ty + i * 8] * scale);
    return;
  }
  // ---- patch embed + LN role ----
  int blk = bid - 2304;
  int b = blk >> 8, nq = blk & 255;
  int t = threadIdx.x;
  {
    int tk = t >> 6, p = t & 63;
    int n = nq * 4 + tk;
    int gi = n >> 5, gj = n & 31;
    pix[tk][p] = sam[b * 65536 + (gi * 8 + (p >> 3)) * 256 + gj * 8 + (p & 7)];
  }
  __syncthreads();
  float acc[3][4];
#pragma unroll
  for (int u = 0; u < 3; u++) {
    int d = t + u * 256;
    const float4* w4 = (const float4*)(cw + (size_t)d * 64);
    float a0 = cb[d];
    float av0 = a0, av1 = a0, av2 = a0, av3 = a0;
#pragma unroll
    for (int pc = 0; pc < 16; pc++) {
      float4 w = w4[pc];
      av0 += w.x * pix[0][pc * 4] + w.y * pix[0][pc * 4 + 1] + w.z * pix[0][pc * 4 + 2] + w.w * pix[0][pc * 4 + 3];
      av1 += w.x * pix[1][pc * 4] + w.y * pix[1][pc * 4 + 1] + w.z * pix[1][pc * 4 + 2] + w.w * pix[1][pc * 4 + 3];
      av2 += w.x * pix[2][pc * 4] + w.y * pix[2][pc * 4 + 1] + w.z * pix[2][pc * 4 + 2] + w.w * pix[2][pc * 4 + 3];
      av3 += w.x * pix[3][pc * 4] + w.y * pix[3][pc * 4 + 1] + w.z * pix[3][pc * 4 + 2] + w.w * pix[3][pc * 4 + 3];
    }
    acc[u][0] = av0; acc[u][1] = av1; acc[u][2] = av2; acc[u][3] = av3;
  }
  float s1[4], s2[4];
#pragma unroll
  for (int tk = 0; tk < 4; tk++) {
    s1[tk] = acc[0][tk] + acc[1][tk] + acc[2][tk];
    s2[tk] = acc[0][tk] * acc[0][tk] + acc[1][tk] * acc[1][tk] + acc[2][tk] * acc[2][tk];
  }
#pragma unroll
  for (int m = 1; m < 64; m <<= 1) {
#pragma unroll
    for (int tk = 0; tk < 4; tk++) {
      s1[tk] += __shfl_xor(s1[tk], m);
      s2[tk] += __shfl_xor(s2[tk], m);
    }
  }
  int wid = t >> 6;
  if ((t & 63) == 0) {
#pragma unroll
    for (int tk = 0; tk < 4; tk++) { red[0][wid][tk] = s1[tk]; red[1][wid][tk] = s2[tk]; }
  }
  __syncthreads();
  float mu[4], rs[4];
#pragma unroll
  for (int tk = 0; tk < 4; tk++) {
    float S1 = red[0][0][tk] + red[0][1][tk] + red[0][2][tk] + red[0][3][tk];
    float S2 = red[1][0][tk] + red[1][1][tk] + red[1][2][tk] + red[1][3][tk];
    mu[tk] = S1 * (1.0f / 768.0f);
    float var = S2 * (1.0f / 768.0f) - mu[tk] * mu[tk];
    rs[tk] = rsqrtf(var + 1e-5f);
  }
#pragma unroll
  for (int u = 0; u < 3; u++) {
    int d = t + u * 256;
    float gg = g[d], bbv = bb[d];
#pragma unroll
    for (int tk = 0; tk < 4; tk++) {
      int n = nq * 4 + tk;
      float val = (acc[u][tk] - mu[tk]) * rs[tk] * gg + bbv + pos[(size_t)n * 768 + d];
      size_t idx = ((size_t)(b * 1024 + n)) * 768 + d;
      x0f[idx] = val;
      x0b[idx] = f2bf(val);
    }
  }
}

// ---------------------------------------------------------------------------
// 128x128 bf16 MFMA GEMM, BK=32, 4 waves, double-buffered LDS prefetch
// (T3-minimum 2-phase: stage t+1 issued after barrier, drained at next barrier).
// EPI 0: qkv scatter epilogue.  EPI 1: proj + bias + residual -> fp32 out.
template <int EPI>
__global__ __launch_bounds__(256, 2) void gemm128(
    const u16* __restrict__ A, const u16* __restrict__ BT, int M, int N, int K,
    u16* __restrict__ q, u16* __restrict__ kk_, u16* __restrict__ vt,
    const float* __restrict__ pb, const float* __restrict__ x0f,
    float* __restrict__ outp) {
  __shared__ __align__(16) u16 Al[2][128 * 32];
  __shared__ __align__(16) u16 Bl[2][128 * 32];
  int m0 = blockIdx.y * 128, n0 = blockIdx.x * 128;
  int tid = threadIdx.x, lane = tid & 63, wid = tid >> 6;
  int wr = wid >> 1, wc = wid & 1;
  f32x4 acc[4][4] = {};
  int arow = lane >> 2, acol = (lane & 3) * 8;
  const u16* ag = A + (size_t)(m0 + wid * 32 + arow) * K + acol;
  const u16* bg = BT + (size_t)(n0 + wid * 32 + arow) * K + acol;
  int lofs = wid * 32 * 32;
#define STAGE_G(bufi, kk)                              \
  do {                                                 \
    GLD16(ag + (kk), &Al[bufi][lofs]);                 \
    GLD16(ag + (kk) + 16 * K, &Al[bufi][lofs + 512]);  \
    GLD16(bg + (kk), &Bl[bufi][lofs]);                 \
    GLD16(bg + (kk) + 16 * K, &Bl[bufi][lofs + 512]);  \
  } while (0)
  STAGE_G(0, 0);
  int nk = K >> 5;
  int cur = 0;
  for (int t = 0; t < nk; t++) {
    __syncthreads();  // drains stage(t) [vmcnt(0)] + cross-wave barrier
    if (t + 1 < nk) STAGE_G(cur ^ 1, (t + 1) * 32);  // async, in flight through compute
    s16x8 af[4], bf[4];
#pragma unroll
    for (int m = 0; m < 4; m++)
      af[m] = *(const s16x8*)&Al[cur][(wr * 64 + m * 16 + (lane & 15)) * 32 + (lane >> 4) * 8];
#pragma unroll
    for (int nn = 0; nn < 4; nn++)
      bf[nn] = *(const s16x8*)&Bl[cur][(wc * 64 + nn * 16 + (lane & 15)) * 32 + (lane >> 4) * 8];
#pragma unroll
    for (int m = 0; m < 4; m++)
#pragma unroll
      for (int nn = 0; nn < 4; nn++)
        acc[m][nn] = MFMA16(af[m], bf[nn], acc[m][nn]);
    cur ^= 1;
  }
#undef STAGE_G
#pragma unroll
  for (int m = 0; m < 4; m++) {
    int rbase = m0 + wr * 64 + m * 16 + ((lane >> 4) << 2);
#pragma unroll
    for (int nn = 0; nn < 4; nn++) {
      int col = n0 + wc * 64 + nn * 16 + (lane & 15);
      f32x4 v = acc[m][nn];
      if (EPI == 0) {
        if (col < 1536) {
          int cc = (col < 768) ? col : col - 768;
          int h = cc / 96, hd = cc % 96;
          u16* dst = (col < 768) ? q : kk_;
          int bq = (rbase >> 10) * 8 + h;
#pragma unroll
          for (int i = 0; i < 4; i++) {
            int row = rbase + i;
            dst[((size_t)bq * 1024 + (row & 1023)) * 96 + hd] = f2bf(v[i]);
          }
        } else {
          int cc = col - 1536;
          int h = cc / 96, hd = cc % 96;
          int bq = (rbase >> 10) * 8 + h;
          ushort4 pk;
          pk.x = f2bf(v[0]); pk.y = f2bf(v[1]); pk.z = f2bf(v[2]); pk.w = f2bf(v[3]);
          *(ushort4*)&vt[((size_t)bq * 96 + hd) * 1024 + (rbase & 1023)] = pk;
        }
      } else {
        float add = pb[col];
#pragma unroll
        for (int i = 0; i < 4; i++) {
          size_t idx = (size_t)(rbase + i) * 768 + col;
          outp[idx] = v[i] + add + x0f[idx];
        }
      }
    }
  }
}

// ---------------------------------------------------------------------------
// Flash attention with T14 async-STAGE (issue loads early, ds_write late).
// grid = 256 (32 bh * 8 q-blocks of 128), 4 waves * 32 q-rows.
__global__ __launch_bounds__(256, 2) void attn_k(
    const u16* __restrict__ qg, const u16* __restrict__ kg,
    const u16* __restrict__ vg, u16* __restrict__ o) {
  int bh = blockIdx.x >> 3, qb = blockIdx.x & 7;
  int b = bh >> 3, h = bh & 7;
  int tid = threadIdx.x, lane = tid & 63, wid = tid >> 6;
  int q0 = qb * 128 + wid * 32;
  s16x8 aq[2][3];
#pragma unroll
  for (int mf = 0; mf < 2; mf++)
#pragma unroll
    for (int kc = 0; kc < 3; kc++)
      aq[mf][kc] = *(const s16x8*)&qg[((size_t)bh * 1024 + q0 + mf * 16 + (lane & 15)) * 96 + kc * 32 + (lane >> 4) * 8];
  float mrun[2][4], lrun[2][4];
  f32x4 accO[2][6] = {};
#pragma unroll
  for (int mf = 0; mf < 2; mf++)
#pragma unroll
    for (int i = 0; i < 4; i++) { mrun[mf][i] = -1e30f; lrun[mf][i] = 0.0f; }
  __shared__ __align__(16) u16 Kl[64][104];
  __shared__ __align__(16) u16 VTl[96][72];
  __shared__ __align__(16) u16 Pl[4][32][72];
  const u16* kbase = kg + (size_t)bh * 1024 * 96;
  const u16* vbase = vg + (size_t)bh * 96 * 1024;
  int kkey[3], koff[3], vhd[3], vko[3];
#pragma unroll
  for (int it = 0; it < 3; it++) {
    int c = it * 256 + tid;
    kkey[it] = c / 12; koff[it] = (c % 12) * 8;
    vhd[it] = c >> 3;  vko[it] = (c & 7) * 8;
  }
  uint4 kreg[3], vreg[3];
#define ALOAD(kt)                                                                        \
  do {                                                                                   \
    _Pragma("unroll") for (int it = 0; it < 3; it++) {                                   \
      kreg[it] = *(const uint4*)&kbase[(size_t)((kt) * 64 + kkey[it]) * 96 + koff[it]];  \
      vreg[it] = *(const uint4*)&vbase[(size_t)vhd[it] * 1024 + (kt) * 64 + vko[it]];    \
    }                                                                                    \
  } while (0)
#define AWRITE()                                             \
  do {                                                       \
    _Pragma("unroll") for (int it = 0; it < 3; it++) {       \
      *(uint4*)&Kl[kkey[it]][koff[it]] = kreg[it];           \
      *(uint4*)&VTl[vhd[it]][vko[it]] = vreg[it];            \
    }                                                        \
  } while (0)
  ALOAD(0);
  AWRITE();
  for (int kt = 0; kt < 16; kt++) {
    if (kt < 15) ALOAD(kt + 1);  // async into regs; lands during compute
    __syncthreads();             // tile kt's ds_writes visible to all waves
    // S = Q K^T
    f32x4 s[2][4] = {};
#pragma unroll
    for (int nf = 0; nf < 4; nf++) {
#pragma unroll
      for (int kc = 0; kc < 3; kc++) {
        s16x8 bk = *(const s16x8*)&Kl[nf * 16 + (lane & 15)][kc * 32 + (lane >> 4) * 8];
        s[0][nf] = MFMA16(aq[0][kc], bk, s[0][nf]);
        s[1][nf] = MFMA16(aq[1][kc], bk, s[1][nf]);
      }
    }
    // online softmax per owned row
#pragma unroll
    for (int mf = 0; mf < 2; mf++) {
#pragma unroll
      for (int i = 0; i < 4; i++) {
        float rm = fmaxf(fmaxf(s[mf][0][i], s[mf][1][i]), fmaxf(s[mf][2][i], s[mf][3][i]));
#pragma unroll
        for (int m = 1; m < 16; m <<= 1) rm = fmaxf(rm, __shfl_xor(rm, m));
        float newm = fmaxf(mrun[mf][i], rm);
        float alpha = __expf(mrun[mf][i] - newm);
        float ps = 0.0f;
#pragma unroll
        for (int nf = 0; nf < 4; nf++) {
          float p = __expf(s[mf][nf][i] - newm);
          s[mf][nf][i] = p;
          ps += p;
        }
#pragma unroll
        for (int m = 1; m < 16; m <<= 1) ps += __shfl_xor(ps, m);
        lrun[mf][i] = lrun[mf][i] * alpha + ps;
        mrun[mf][i] = newm;
#pragma unroll
        for (int nf = 0; nf < 6; nf++) accO[mf][nf][i] *= alpha;
      }
#pragma unroll
      for (int nf = 0; nf < 4; nf++)
#pragma unroll
        for (int i = 0; i < 4; i++)
          Pl[wid][mf * 16 + ((lane >> 4) << 2) + i][nf * 16 + (lane & 15)] = f2bf(s[mf][nf][i]);
    }
    asm volatile("s_waitcnt lgkmcnt(0)" ::: "memory");
    __builtin_amdgcn_sched_barrier(0);
    // O += P V
#pragma unroll
    for (int kc = 0; kc < 2; kc++) {
      s16x8 ap0 = *(const s16x8*)&Pl[wid][0 + (lane & 15)][kc * 32 + (lane >> 4) * 8];
      s16x8 ap1 = *(const s16x8*)&Pl[wid][16 + (lane & 15)][kc * 32 + (lane >> 4) * 8];
#pragma unroll
      for (int nf = 0; nf < 6; nf++) {
        s16x8 bv = *(const s16x8*)&VTl[nf * 16 + (lane & 15)][kc * 32 + (lane >> 4) * 8];
        accO[0][nf] = MFMA16(ap0, bv, accO[0][nf]);
        accO[1][nf] = MFMA16(ap1, bv, accO[1][nf]);
      }
    }
    __syncthreads();  // all reads of tile kt done
    if (kt < 15) AWRITE();  // ds_write tile kt+1 (auto vmcnt-wait on kreg/vreg)
  }
#undef ALOAD
#undef AWRITE
#pragma unroll
  for (int mf = 0; mf < 2; mf++) {
#pragma unroll
    for (int i = 0; i < 4; i++) {
      float inv = 1.0f / lrun[mf][i];
      int tok = qb * 128 + wid * 32 + mf * 16 + ((lane >> 4) << 2) + i;
      u16* orow = o + ((size_t)(b * 1024 + tok)) * 768 + h * 96;
#pragma unroll
      for (int nf = 0; nf < 6; nf++)
        orow[nf * 16 + (lane & 15)] = f2bf(accO[mf][nf][i] * inv);
    }
  }
}

// ---------------------------------------------------------------------------
extern "C" void kernel_launch(void* const* d_in, const int* in_sizes, int n_in,
                              void* d_out, int out_size, void* d_ws, size_t ws_size,
                              hipStream_t stream) {
  const float* sam    = (const float*)d_in[0];
  const float* conv_w = (const float*)d_in[1];
  const float* conv_b = (const float*)d_in[2];
  const float* ln_g   = (const float*)d_in[3];
  const float* ln_b   = (const float*)d_in[4];
  const float* pos    = (const float*)d_in[5];
  const float* q_w    = (const float*)d_in[6] + (size_t)20 * 768 * 768;
  const float* kv_w   = (const float*)d_in[7] + (size_t)20 * 768 * 1536;
  const float* proj_w = (const float*)d_in[8] + (size_t)20 * 768 * 768;
  const float* proj_b = (const float*)d_in[9] + (size_t)20 * 768;

  char* ws = (char*)d_ws;
  float* x0f  = (float*)ws; ws += (size_t)4096 * 768 * 4;
  u16* x0b    = (u16*)ws;   ws += (size_t)4096 * 768 * 2;
  u16* wqkvT  = (u16*)ws;   ws += (size_t)2304 * 768 * 2;
  u16* pwT    = (u16*)ws;   ws += (size_t)768 * 768 * 2;
  u16* qs     = (u16*)ws;   ws += (size_t)32 * 1024 * 96 * 2;
  u16* ks     = (u16*)ws;   ws += (size_t)32 * 1024 * 96 * 2;
  u16* vts    = (u16*)ws;   ws += (size_t)32 * 96 * 1024 * 2;
  u16* ob     = (u16*)ws;   ws += (size_t)4096 * 768 * 2;

  prep_k<<<3328, 256, 0, stream>>>(q_w, kv_w, proj_w, wqkvT, pwT, sam, conv_w,
                                   conv_b, ln_g, ln_b, pos, x0f, x0b);
  dim3 g1(18, 32);
  gemm128<0><<<g1, 256, 0, stream>>>(x0b, wqkvT, 4096, 2304, 768, qs, ks, vts,
                                     nullptr, nullptr, nullptr);
  attn_k<<<256, 256, 0, stream>>>(qs, ks, vts, ob);
  dim3 g2(6, 32);
  gemm128<1><<<g2, 256, 0, stream>>>(ob, pwT, 4096, 768, 768, nullptr, nullptr,
                                     nullptr, proj_b, x0f, (float*)d_out);
}

// Round 4
// 337.518 us; speedup vs baseline: 1.0559x; 1.0559x over previous
//
#include <hip/hip_runtime.h>
#include <hip/hip_bf16.h>

typedef __attribute__((ext_vector_type(4))) float f32x4;
typedef __attribute__((ext_vector_type(8))) short s16x8;
typedef unsigned short u16;
typedef unsigned int u32;

#define DEV __device__ __forceinline__

DEV u16 f2bf(float f) {
  union { float f; u32 u; } v; v.f = f;
  u32 r = v.u + 0x7fffu + ((v.u >> 16) & 1u);
  return (u16)(r >> 16);
}

#define MFMA16(a, b, c) __builtin_amdgcn_mfma_f32_16x16x32_bf16((a), (b), (c), 0, 0, 0)
#define GLD16(g, l) __builtin_amdgcn_global_load_lds((const __attribute__((address_space(1))) u32*)(g), (__attribute__((address_space(3))) u32*)(l), 16, 0, 0)

#define QSCALE 0.10206207261596577f  // 96^-0.5

// ---------------------------------------------------------------------------
// Fused prep kernel.
//  blocks [0, 2304):  transpose-cast fp32 [768][ncols] -> bf16 [ncols][768]
//  blocks [2304, 3328): patch embed conv + LayerNorm + pos -> x0 fp32 + bf16
__global__ __launch_bounds__(256) void prep_k(
    const float* __restrict__ qw, const float* __restrict__ kvw,
    const float* __restrict__ pw, u16* __restrict__ wqkvT, u16* __restrict__ pwT,
    const float* __restrict__ sam, const float* __restrict__ cw,
    const float* __restrict__ cb, const float* __restrict__ g,
    const float* __restrict__ bb, const float* __restrict__ pos,
    float* __restrict__ x0f, u16* __restrict__ x0b) {
  __shared__ float tb[32][33];
  __shared__ float pix[4][64];
  __shared__ float red[2][4][4];
  int bid = blockIdx.x;
  if (bid < 2304) {
    int ct = bid / 24, kt = (bid % 24) * 32;
    const float* src;
    u16* dst;
    int ncols, tn, dstbase;
    float scale = 1.0f;
    if (ct < 24) {
      src = qw; ncols = 768; tn = ct * 32; dst = wqkvT; dstbase = tn; scale = QSCALE;
    } else if (ct < 72) {
      src = kvw; ncols = 1536; tn = (ct - 24) * 32; dst = wqkvT; dstbase = 768 + tn;
    } else {
      src = pw; ncols = 768; tn = (ct - 72) * 32; dst = pwT; dstbase = tn;
    }
    int tx = threadIdx.x & 31, ty = threadIdx.x >> 5;
#pragma unroll
    for (int i = 0; i < 4; i++)
      tb[ty + i * 8][tx] = src[(size_t)(kt + ty + i * 8) * ncols + tn + tx];
    __syncthreads();
#pragma unroll
    for (int i = 0; i < 4; i++)
      dst[(size_t)(dstbase + ty + i * 8) * 768 + kt + tx] = f2bf(tb[tx][ty + i * 8] * scale);
    return;
  }
  int blk = bid - 2304;
  int b = blk >> 8, nq = blk & 255;
  int t = threadIdx.x;
  {
    int tk = t >> 6, p = t & 63;
    int n = nq * 4 + tk;
    int gi = n >> 5, gj = n & 31;
    pix[tk][p] = sam[b * 65536 + (gi * 8 + (p >> 3)) * 256 + gj * 8 + (p & 7)];
  }
  __syncthreads();
  float acc[3][4];
#pragma unroll
  for (int u = 0; u < 3; u++) {
    int d = t + u * 256;
    const float4* w4 = (const float4*)(cw + (size_t)d * 64);
    float a0 = cb[d];
    float av0 = a0, av1 = a0, av2 = a0, av3 = a0;
#pragma unroll
    for (int pc = 0; pc < 16; pc++) {
      float4 w = w4[pc];
      av0 += w.x * pix[0][pc * 4] + w.y * pix[0][pc * 4 + 1] + w.z * pix[0][pc * 4 + 2] + w.w * pix[0][pc * 4 + 3];
      av1 += w.x * pix[1][pc * 4] + w.y * pix[1][pc * 4 + 1] + w.z * pix[1][pc * 4 + 2] + w.w * pix[1][pc * 4 + 3];
      av2 += w.x * pix[2][pc * 4] + w.y * pix[2][pc * 4 + 1] + w.z * pix[2][pc * 4 + 2] + w.w * pix[2][pc * 4 + 3];
      av3 += w.x * pix[3][pc * 4] + w.y * pix[3][pc * 4 + 1] + w.z * pix[3][pc * 4 + 2] + w.w * pix[3][pc * 4 + 3];
    }
    acc[u][0] = av0; acc[u][1] = av1; acc[u][2] = av2; acc[u][3] = av3;
  }
  float s1[4], s2[4];
#pragma unroll
  for (int tk = 0; tk < 4; tk++) {
    s1[tk] = acc[0][tk] + acc[1][tk] + acc[2][tk];
    s2[tk] = acc[0][tk] * acc[0][tk] + acc[1][tk] * acc[1][tk] + acc[2][tk] * acc[2][tk];
  }
#pragma unroll
  for (int m = 1; m < 64; m <<= 1) {
#pragma unroll
    for (int tk = 0; tk < 4; tk++) {
      s1[tk] += __shfl_xor(s1[tk], m);
      s2[tk] += __shfl_xor(s2[tk], m);
    }
  }
  int wid = t >> 6;
  if ((t & 63) == 0) {
#pragma unroll
    for (int tk = 0; tk < 4; tk++) { red[0][wid][tk] = s1[tk]; red[1][wid][tk] = s2[tk]; }
  }
  __syncthreads();
  float mu[4], rs[4];
#pragma unroll
  for (int tk = 0; tk < 4; tk++) {
    float S1 = red[0][0][tk] + red[0][1][tk] + red[0][2][tk] + red[0][3][tk];
    float S2 = red[1][0][tk] + red[1][1][tk] + red[1][2][tk] + red[1][3][tk];
    mu[tk] = S1 * (1.0f / 768.0f);
    float var = S2 * (1.0f / 768.0f) - mu[tk] * mu[tk];
    rs[tk] = rsqrtf(var + 1e-5f);
  }
#pragma unroll
  for (int u = 0; u < 3; u++) {
    int d = t + u * 256;
    float gg = g[d], bbv = bb[d];
#pragma unroll
    for (int tk = 0; tk < 4; tk++) {
      int n = nq * 4 + tk;
      float val = (acc[u][tk] - mu[tk]) * rs[tk] * gg + bbv + pos[(size_t)n * 768 + d];
      size_t idx = ((size_t)(b * 1024 + n)) * 768 + d;
      x0f[idx] = val;
      x0b[idx] = f2bf(val);
    }
  }
}

// ---------------------------------------------------------------------------
// 128x128 bf16 MFMA GEMM, BK=32, 4 waves, double-buffered LDS prefetch.
// EPI 0: qkv scatter epilogue.  EPI 1: proj + bias + residual -> fp32 out.
template <int EPI>
__global__ __launch_bounds__(256, 2) void gemm128(
    const u16* __restrict__ A, const u16* __restrict__ BT, int M, int N, int K,
    u16* __restrict__ q, u16* __restrict__ kk_, u16* __restrict__ vt,
    const float* __restrict__ pb, const float* __restrict__ x0f,
    float* __restrict__ outp) {
  __shared__ __align__(16) u16 Al[2][128 * 32];
  __shared__ __align__(16) u16 Bl[2][128 * 32];
  int m0 = blockIdx.y * 128, n0 = blockIdx.x * 128;
  int tid = threadIdx.x, lane = tid & 63, wid = tid >> 6;
  int wr = wid >> 1, wc = wid & 1;
  f32x4 acc[4][4] = {};
  int arow = lane >> 2, acol = (lane & 3) * 8;
  const u16* ag = A + (size_t)(m0 + wid * 32 + arow) * K + acol;
  const u16* bg = BT + (size_t)(n0 + wid * 32 + arow) * K + acol;
  int lofs = wid * 32 * 32;
#define STAGE_G(bufi, kk)                              \
  do {                                                 \
    GLD16(ag + (kk), &Al[bufi][lofs]);                 \
    GLD16(ag + (kk) + 16 * K, &Al[bufi][lofs + 512]);  \
    GLD16(bg + (kk), &Bl[bufi][lofs]);                 \
    GLD16(bg + (kk) + 16 * K, &Bl[bufi][lofs + 512]);  \
  } while (0)
  STAGE_G(0, 0);
  int nk = K >> 5;
  int cur = 0;
  for (int t = 0; t < nk; t++) {
    __syncthreads();
    if (t + 1 < nk) STAGE_G(cur ^ 1, (t + 1) * 32);
    s16x8 af[4], bf[4];
#pragma unroll
    for (int m = 0; m < 4; m++)
      af[m] = *(const s16x8*)&Al[cur][(wr * 64 + m * 16 + (lane & 15)) * 32 + (lane >> 4) * 8];
#pragma unroll
    for (int nn = 0; nn < 4; nn++)
      bf[nn] = *(const s16x8*)&Bl[cur][(wc * 64 + nn * 16 + (lane & 15)) * 32 + (lane >> 4) * 8];
#pragma unroll
    for (int m = 0; m < 4; m++)
#pragma unroll
      for (int nn = 0; nn < 4; nn++)
        acc[m][nn] = MFMA16(af[m], bf[nn], acc[m][nn]);
    cur ^= 1;
  }
#undef STAGE_G
#pragma unroll
  for (int m = 0; m < 4; m++) {
    int rbase = m0 + wr * 64 + m * 16 + ((lane >> 4) << 2);
#pragma unroll
    for (int nn = 0; nn < 4; nn++) {
      int col = n0 + wc * 64 + nn * 16 + (lane & 15);
      f32x4 v = acc[m][nn];
      if (EPI == 0) {
        if (col < 1536) {
          int cc = (col < 768) ? col : col - 768;
          int h = cc / 96, hd = cc % 96;
          u16* dst = (col < 768) ? q : kk_;
          int bq = (rbase >> 10) * 8 + h;
#pragma unroll
          for (int i = 0; i < 4; i++) {
            int row = rbase + i;
            dst[((size_t)bq * 1024 + (row & 1023)) * 96 + hd] = f2bf(v[i]);
          }
        } else {
          int cc = col - 1536;
          int h = cc / 96, hd = cc % 96;
          int bq = (rbase >> 10) * 8 + h;
          ushort4 pk;
          pk.x = f2bf(v[0]); pk.y = f2bf(v[1]); pk.z = f2bf(v[2]); pk.w = f2bf(v[3]);
          *(ushort4*)&vt[((size_t)bq * 96 + hd) * 1024 + (rbase & 1023)] = pk;
        }
      } else {
        float add = pb[col];
#pragma unroll
        for (int i = 0; i < 4; i++) {
          size_t idx = (size_t)(rbase + i) * 768 + col;
          outp[idx] = v[i] + add + x0f[idx];
        }
      }
    }
  }
}

// ---------------------------------------------------------------------------
// Flash attention v3: 64-row q-blocks (grid 512 = 2 blocks/CU), XCD swizzle,
// K staged in LDS, V fragments DIRECT from global (L2-resident), defer-rescale.
// q,k: [bh][n][96] bf16 (q pre-scaled). vt: [bh][96][n] bf16. o: [b*1024+n][768].
__global__ __launch_bounds__(256, 2) void attn_k(
    const u16* __restrict__ qg, const u16* __restrict__ kg,
    const u16* __restrict__ vg, u16* __restrict__ o) {
  // bijective XCD swizzle: XCD x serves bh {4x..4x+3} (K/V stay L2-local)
  int newid = ((blockIdx.x & 7) << 6) + (blockIdx.x >> 3);
  int bh = newid >> 4, qb = newid & 15;
  int b = bh >> 3, h = bh & 7;
  int tid = threadIdx.x, lane = tid & 63, wid = tid >> 6;
  int l15 = lane & 15, l4 = lane >> 4;
  int q0 = qb * 64 + wid * 16;
  const u16* qbase = qg + (size_t)bh * 1024 * 96;
  const u16* kbase = kg + (size_t)bh * 1024 * 96;
  const u16* vbase = vg + (size_t)bh * 96 * 1024;
  s16x8 aq[3];
#pragma unroll
  for (int kc = 0; kc < 3; kc++)
    aq[kc] = *(const s16x8*)&qbase[(size_t)(q0 + l15) * 96 + kc * 32 + l4 * 8];
  float mrun[4], lrun[4];
  f32x4 accO[6] = {};
#pragma unroll
  for (int i = 0; i < 4; i++) { mrun[i] = -1e30f; lrun[i] = 0.0f; }
  __shared__ __align__(16) u16 Kl[64][104];
  __shared__ __align__(16) u16 Pl[4][16][72];
  int kkey[3], koff[3];
#pragma unroll
  for (int it = 0; it < 3; it++) {
    int c = it * 256 + tid;
    kkey[it] = c / 12; koff[it] = (c % 12) * 8;
  }
  for (int kt = 0; kt < 16; kt++) {
    // stage K tile (64 keys x 96 d) via regs into padded LDS
#pragma unroll
    for (int it = 0; it < 3; it++)
      *(uint4*)&Kl[kkey[it]][koff[it]] =
          *(const uint4*)&kbase[(size_t)(kt * 64 + kkey[it]) * 96 + koff[it]];
    __syncthreads();
    // V fragments direct from global — independent, in flight under QK+softmax
    s16x8 bv[6][2];
#pragma unroll
    for (int nf = 0; nf < 6; nf++)
#pragma unroll
      for (int kc = 0; kc < 2; kc++)
        bv[nf][kc] = *(const s16x8*)&vbase[(size_t)(nf * 16 + l15) * 1024 +
                                           kt * 64 + kc * 32 + l4 * 8];
    // S = Q K^T : 16 q-rows x 64 keys per wave
    f32x4 s4[4] = {};
    __builtin_amdgcn_s_setprio(1);
#pragma unroll
    for (int nf = 0; nf < 4; nf++)
#pragma unroll
      for (int kc = 0; kc < 3; kc++) {
        s16x8 bk = *(const s16x8*)&Kl[nf * 16 + l15][kc * 32 + l4 * 8];
        s4[nf] = MFMA16(aq[kc], bk, s4[nf]);
      }
    __builtin_amdgcn_s_setprio(0);
    // online softmax (rows: q=(l4)*4+i, keys across nf & l15)
    float rm[4];
#pragma unroll
    for (int i = 0; i < 4; i++) {
      rm[i] = fmaxf(fmaxf(s4[0][i], s4[1][i]), fmaxf(s4[2][i], s4[3][i]));
#pragma unroll
      for (int m = 1; m < 16; m <<= 1) rm[i] = fmaxf(rm[i], __shfl_xor(rm[i], m));
    }
    bool need = (rm[0] > mrun[0]) || (rm[1] > mrun[1]) ||
                (rm[2] > mrun[2]) || (rm[3] > mrun[3]);
    if (__any(need)) {
#pragma unroll
      for (int i = 0; i < 4; i++) {
        float newm = fmaxf(mrun[i], rm[i]);
        float al = __expf(mrun[i] - newm);
        mrun[i] = newm;
        lrun[i] *= al;
#pragma unroll
        for (int nf = 0; nf < 6; nf++) accO[nf][i] *= al;
      }
    }
#pragma unroll
    for (int i = 0; i < 4; i++) {
      float ps = 0.0f;
#pragma unroll
      for (int nf = 0; nf < 4; nf++) {
        float p = __expf(s4[nf][i] - mrun[i]);
        s4[nf][i] = p;
        ps += p;
      }
#pragma unroll
      for (int m = 1; m < 16; m <<= 1) ps += __shfl_xor(ps, m);
      lrun[i] += ps;
    }
    // P -> LDS (per-wave private; within-wave fence below)
#pragma unroll
    for (int nf = 0; nf < 4; nf++)
#pragma unroll
      for (int i = 0; i < 4; i++)
        Pl[wid][l4 * 4 + i][nf * 16 + l15] = f2bf(s4[nf][i]);
    asm volatile("s_waitcnt lgkmcnt(0)" ::: "memory");
    __builtin_amdgcn_sched_barrier(0);
    // O += P V (V from regs, A from Pl)
    __builtin_amdgcn_s_setprio(1);
#pragma unroll
    for (int kc = 0; kc < 2; kc++) {
      s16x8 ap = *(const s16x8*)&Pl[wid][l15][kc * 32 + l4 * 8];
#pragma unroll
      for (int nf = 0; nf < 6; nf++)
        accO[nf] = MFMA16(ap, bv[nf][kc], accO[nf]);
    }
    __builtin_amdgcn_s_setprio(0);
    __syncthreads();
  }
#pragma unroll
  for (int i = 0; i < 4; i++) {
    float inv = 1.0f / lrun[i];
    int tok = q0 + l4 * 4 + i;
    u16* orow = o + ((size_t)(b * 1024 + tok)) * 768 + h * 96;
#pragma unroll
    for (int nf = 0; nf < 6; nf++)
      orow[nf * 16 + l15] = f2bf(accO[nf][i] * inv);
  }
}

// ---------------------------------------------------------------------------
extern "C" void kernel_launch(void* const* d_in, const int* in_sizes, int n_in,
                              void* d_out, int out_size, void* d_ws, size_t ws_size,
                              hipStream_t stream) {
  const float* sam    = (const float*)d_in[0];
  const float* conv_w = (const float*)d_in[1];
  const float* conv_b = (const float*)d_in[2];
  const float* ln_g   = (const float*)d_in[3];
  const float* ln_b   = (const float*)d_in[4];
  const float* pos    = (const float*)d_in[5];
  const float* q_w    = (const float*)d_in[6] + (size_t)20 * 768 * 768;
  const float* kv_w   = (const float*)d_in[7] + (size_t)20 * 768 * 1536;
  const float* proj_w = (const float*)d_in[8] + (size_t)20 * 768 * 768;
  const float* proj_b = (const float*)d_in[9] + (size_t)20 * 768;

  char* ws = (char*)d_ws;
  float* x0f  = (float*)ws; ws += (size_t)4096 * 768 * 4;
  u16* x0b    = (u16*)ws;   ws += (size_t)4096 * 768 * 2;
  u16* wqkvT  = (u16*)ws;   ws += (size_t)2304 * 768 * 2;
  u16* pwT    = (u16*)ws;   ws += (size_t)768 * 768 * 2;
  u16* qs     = (u16*)ws;   ws += (size_t)32 * 1024 * 96 * 2;
  u16* ks     = (u16*)ws;   ws += (size_t)32 * 1024 * 96 * 2;
  u16* vts    = (u16*)ws;   ws += (size_t)32 * 96 * 1024 * 2;
  u16* ob     = (u16*)ws;   ws += (size_t)4096 * 768 * 2;

  prep_k<<<3328, 256, 0, stream>>>(q_w, kv_w, proj_w, wqkvT, pwT, sam, conv_w,
                                   conv_b, ln_g, ln_b, pos, x0f, x0b);
  dim3 g1(18, 32);
  gemm128<0><<<g1, 256, 0, stream>>>(x0b, wqkvT, 4096, 2304, 768, qs, ks, vts,
                                     nullptr, nullptr, nullptr);
  attn_k<<<512, 256, 0, stream>>>(qs, ks, vts, ob);
  dim3 g2(6, 32);
  gemm128<1><<<g2, 256, 0, stream>>>(ob, pwT, 4096, 768, 768, nullptr, nullptr,
                                     nullptr, proj_b, x0f, (float*)d_out);
}

// Round 5
// 296.012 us; speedup vs baseline: 1.2039x; 1.1402x over previous
//
#include <hip/hip_runtime.h>
#include <hip/hip_bf16.h>

typedef __attribute__((ext_vector_type(4))) float f32x4;
typedef __attribute__((ext_vector_type(8))) short s16x8;
typedef unsigned short u16;
typedef unsigned int u32;

#define DEV __device__ __forceinline__

DEV u16 f2bf(float f) {
  union { float f; u32 u; } v; v.f = f;
  u32 r = v.u + 0x7fffu + ((v.u >> 16) & 1u);
  return (u16)(r >> 16);
}
DEV float bf2f(u16 h) {
  union { u32 u; float f; } v; v.u = ((u32)h) << 16;
  return v.f;
}

#define MFMA16(a, b, c) __builtin_amdgcn_mfma_f32_16x16x32_bf16((a), (b), (c), 0, 0, 0)
#define GLD16(g, l) __builtin_amdgcn_global_load_lds((const __attribute__((address_space(1))) u32*)(g), (__attribute__((address_space(3))) u32*)(l), 16, 0, 0)

#define QSCALE 0.10206207261596577f  // 96^-0.5

// ---------------------------------------------------------------------------
// prep0_k:
//  blocks [0,2304):    transpose-cast fp32 [768][ncols] -> bf16 [ncols][768]
//  blocks [2304,2316): conv_w fp32 [768][64] -> bf16 swizzled (k ^ ((n&7)<<3))
//  blocks [2316,2444): im2col: sam -> apx [4096 tokens][64 px] bf16
__global__ __launch_bounds__(256) void prep0_k(
    const float* __restrict__ qw, const float* __restrict__ kvw,
    const float* __restrict__ pw, u16* __restrict__ wqkvT, u16* __restrict__ pwT,
    const float* __restrict__ cw, u16* __restrict__ cwb,
    const float* __restrict__ sam, u16* __restrict__ apx) {
  __shared__ float tb[32][33];
  int bid = blockIdx.x;
  int tid = threadIdx.x;
  if (bid < 2304) {
    int ct = bid / 24, kt = (bid % 24) * 32;
    const float* src;
    u16* dst;
    int ncols, tn, dstbase;
    float scale = 1.0f;
    if (ct < 24) {
      src = qw; ncols = 768; tn = ct * 32; dst = wqkvT; dstbase = tn; scale = QSCALE;
    } else if (ct < 72) {
      src = kvw; ncols = 1536; tn = (ct - 24) * 32; dst = wqkvT; dstbase = 768 + tn;
    } else {
      src = pw; ncols = 768; tn = (ct - 72) * 32; dst = pwT; dstbase = tn;
    }
    int tx = tid & 31, ty = tid >> 5;
#pragma unroll
    for (int i = 0; i < 4; i++)
      tb[ty + i * 8][tx] = src[(size_t)(kt + ty + i * 8) * ncols + tn + tx];
    __syncthreads();
#pragma unroll
    for (int i = 0; i < 4; i++)
      dst[(size_t)(dstbase + ty + i * 8) * 768 + kt + tx] = f2bf(tb[tx][ty + i * 8] * scale);
    return;
  }
  if (bid < 2316) {
    // conv_w cast + swizzle: 4096 elems per block, 16 per thread (one row chunk)
    int e0 = (bid - 2304) * 4096 + tid * 16;
    int n = e0 >> 6, k0 = e0 & 63;
    int sx = (n & 7) << 3;
    u16 tmp[16];
#pragma unroll
    for (int j = 0; j < 16; j++) tmp[j] = f2bf(cw[e0 + j]);
#pragma unroll
    for (int h = 0; h < 2; h++)
      *(uint4*)&cwb[n * 64 + ((k0 + h * 8) ^ sx)] = *(const uint4*)&tmp[h * 8];
    return;
  }
  // im2col: one (b, gi) strip = 32 tokens
  int blk = bid - 2316;
  int b = blk >> 5, gi = blk & 31;
  const float* srow = sam + ((size_t)b * 256 + gi * 8) * 256;
  int gj = tid >> 3, c = tid & 7;
#pragma unroll
  for (int r = 0; r < 8; r++) {
    float v = srow[r * 256 + tid];
    apx[((size_t)b * 1024 + gi * 32 + gj) * 64 + r * 8 + c] = f2bf(v);
  }
}

// ---------------------------------------------------------------------------
// convln_k: fused patch-embed GEMM (M=16/block, N=768, K=64) + bias + LN + pos.
// grid = 256 blocks (1/CU), 4 waves; wave w owns cols [192w, 192w+192).
__global__ __launch_bounds__(256) void convln_k(
    const u16* __restrict__ apx, const u16* __restrict__ cwb,
    const float* __restrict__ cb, const float* __restrict__ g,
    const float* __restrict__ bb, const float* __restrict__ pos,
    u16* __restrict__ x0b) {
  __shared__ __align__(16) u16 Bl[768 * 64];
  __shared__ __align__(16) u16 Al[16 * 72];
  __shared__ float red[4][16][2];
  int tid = threadIdx.x, lane = tid & 63, wid = tid >> 6;
  int l15 = lane & 15, l4 = lane >> 4;
  int tok0 = blockIdx.x * 16;
  {
    const u16* gsrc = cwb + wid * 512 + lane * 8;
    u16* ldst = Bl + wid * 512;
#pragma unroll
    for (int it = 0; it < 24; it++)
      GLD16(gsrc + it * 2048, ldst + it * 2048);
  }
  if (tid < 128) {
    int row = tid >> 3, ch = (tid & 7) * 8;
    *(uint4*)&Al[row * 72 + ch] = *(const uint4*)&apx[(size_t)(tok0 + row) * 64 + ch];
  }
  __syncthreads();
  s16x8 af[2];
#pragma unroll
  for (int kc = 0; kc < 2; kc++)
    af[kc] = *(const s16x8*)&Al[l15 * 72 + kc * 32 + l4 * 8];
  f32x4 s[12];
#pragma unroll
  for (int nt = 0; nt < 12; nt++) {
    int row = wid * 192 + nt * 16 + l15;
    int sx = (row & 7) << 3;
    s16x8 b0 = *(const s16x8*)&Bl[row * 64 + ((l4 * 8) ^ sx)];
    s16x8 b1 = *(const s16x8*)&Bl[row * 64 + ((32 + l4 * 8) ^ sx)];
    f32x4 a = {};
    a = MFMA16(af[0], b0, a);
    a = MFMA16(af[1], b1, a);
    s[nt] = a;
  }
  // bias + LN stats (rows: tok0 + l4*4 + i)
  float p1[4] = {0, 0, 0, 0}, p2[4] = {0, 0, 0, 0};
#pragma unroll
  for (int nt = 0; nt < 12; nt++) {
    float cbv = cb[wid * 192 + nt * 16 + l15];
#pragma unroll
    for (int i = 0; i < 4; i++) {
      float y = s[nt][i] + cbv;
      s[nt][i] = y;
      p1[i] += y;
      p2[i] += y * y;
    }
  }
#pragma unroll
  for (int m = 1; m < 16; m <<= 1)
#pragma unroll
    for (int i = 0; i < 4; i++) {
      p1[i] += __shfl_xor(p1[i], m);
      p2[i] += __shfl_xor(p2[i], m);
    }
  if (l15 == 0)
#pragma unroll
    for (int i = 0; i < 4; i++) {
      red[wid][l4 * 4 + i][0] = p1[i];
      red[wid][l4 * 4 + i][1] = p2[i];
    }
  __syncthreads();
  float mu[4], rs[4];
#pragma unroll
  for (int i = 0; i < 4; i++) {
    int row = l4 * 4 + i;
    float S1 = red[0][row][0] + red[1][row][0] + red[2][row][0] + red[3][row][0];
    float S2 = red[0][row][1] + red[1][row][1] + red[2][row][1] + red[3][row][1];
    mu[i] = S1 * (1.0f / 768.0f);
    float var = S2 * (1.0f / 768.0f) - mu[i] * mu[i];
    rs[i] = rsqrtf(var + 1e-5f);
  }
#pragma unroll
  for (int nt = 0; nt < 12; nt++) {
    int col = wid * 192 + nt * 16 + l15;
    float gg = g[col], bbv = bb[col];
#pragma unroll
    for (int i = 0; i < 4; i++) {
      int tok = tok0 + l4 * 4 + i;
      float val = (s[nt][i] - mu[i]) * rs[i] * gg + bbv +
                  pos[(size_t)(tok & 1023) * 768 + col];
      x0b[(size_t)tok * 768 + col] = f2bf(val);
    }
  }
}

// ---------------------------------------------------------------------------
// 128x128 bf16 MFMA GEMM, BK=32, 4 waves, double-buffered LDS prefetch.
// EPI 0: qkv scatter epilogue.  EPI 1: proj + bias + bf16 residual -> fp32 out.
template <int EPI>
__global__ __launch_bounds__(256, 2) void gemm128(
    const u16* __restrict__ A, const u16* __restrict__ BT, int M, int N, int K,
    u16* __restrict__ q, u16* __restrict__ kk_, u16* __restrict__ vt,
    const float* __restrict__ pb, const u16* __restrict__ resb,
    float* __restrict__ outp) {
  __shared__ __align__(16) u16 Al[2][128 * 32];
  __shared__ __align__(16) u16 Bl[2][128 * 32];
  int m0 = blockIdx.y * 128, n0 = blockIdx.x * 128;
  int tid = threadIdx.x, lane = tid & 63, wid = tid >> 6;
  int wr = wid >> 1, wc = wid & 1;
  f32x4 acc[4][4] = {};
  int arow = lane >> 2, acol = (lane & 3) * 8;
  const u16* ag = A + (size_t)(m0 + wid * 32 + arow) * K + acol;
  const u16* bg = BT + (size_t)(n0 + wid * 32 + arow) * K + acol;
  int lofs = wid * 32 * 32;
#define STAGE_G(bufi, kk)                              \
  do {                                                 \
    GLD16(ag + (kk), &Al[bufi][lofs]);                 \
    GLD16(ag + (kk) + 16 * K, &Al[bufi][lofs + 512]);  \
    GLD16(bg + (kk), &Bl[bufi][lofs]);                 \
    GLD16(bg + (kk) + 16 * K, &Bl[bufi][lofs + 512]);  \
  } while (0)
  STAGE_G(0, 0);
  int nk = K >> 5;
  int cur = 0;
  for (int t = 0; t < nk; t++) {
    __syncthreads();
    if (t + 1 < nk) STAGE_G(cur ^ 1, (t + 1) * 32);
    s16x8 af[4], bf[4];
#pragma unroll
    for (int m = 0; m < 4; m++)
      af[m] = *(const s16x8*)&Al[cur][(wr * 64 + m * 16 + (lane & 15)) * 32 + (lane >> 4) * 8];
#pragma unroll
    for (int nn = 0; nn < 4; nn++)
      bf[nn] = *(const s16x8*)&Bl[cur][(wc * 64 + nn * 16 + (lane & 15)) * 32 + (lane >> 4) * 8];
#pragma unroll
    for (int m = 0; m < 4; m++)
#pragma unroll
      for (int nn = 0; nn < 4; nn++)
        acc[m][nn] = MFMA16(af[m], bf[nn], acc[m][nn]);
    cur ^= 1;
  }
#undef STAGE_G
#pragma unroll
  for (int m = 0; m < 4; m++) {
    int rbase = m0 + wr * 64 + m * 16 + ((lane >> 4) << 2);
#pragma unroll
    for (int nn = 0; nn < 4; nn++) {
      int col = n0 + wc * 64 + nn * 16 + (lane & 15);
      f32x4 v = acc[m][nn];
      if (EPI == 0) {
        if (col < 1536) {
          int cc = (col < 768) ? col : col - 768;
          int h = cc / 96, hd = cc % 96;
          u16* dst = (col < 768) ? q : kk_;
          int bq = (rbase >> 10) * 8 + h;
#pragma unroll
          for (int i = 0; i < 4; i++) {
            int row = rbase + i;
            dst[((size_t)bq * 1024 + (row & 1023)) * 96 + hd] = f2bf(v[i]);
          }
        } else {
          int cc = col - 1536;
          int h = cc / 96, hd = cc % 96;
          int bq = (rbase >> 10) * 8 + h;
          ushort4 pk;
          pk.x = f2bf(v[0]); pk.y = f2bf(v[1]); pk.z = f2bf(v[2]); pk.w = f2bf(v[3]);
          *(ushort4*)&vt[((size_t)bq * 96 + hd) * 1024 + (rbase & 1023)] = pk;
        }
      } else {
        float add = pb[col];
#pragma unroll
        for (int i = 0; i < 4; i++) {
          size_t idx = (size_t)(rbase + i) * 768 + col;
          outp[idx] = v[i] + add + bf2f(resb[idx]);
        }
      }
    }
  }
}

// ---------------------------------------------------------------------------
// Flash attention: 64-row q-blocks (grid 512 = 2 blocks/CU), XCD swizzle,
// K staged in LDS, V fragments DIRECT from global (L2-resident), defer-rescale.
__global__ __launch_bounds__(256, 2) void attn_k(
    const u16* __restrict__ qg, const u16* __restrict__ kg,
    const u16* __restrict__ vg, u16* __restrict__ o) {
  int newid = ((blockIdx.x & 7) << 6) + (blockIdx.x >> 3);
  int bh = newid >> 4, qb = newid & 15;
  int b = bh >> 3, h = bh & 7;
  int tid = threadIdx.x, lane = tid & 63, wid = tid >> 6;
  int l15 = lane & 15, l4 = lane >> 4;
  int q0 = qb * 64 + wid * 16;
  const u16* qbase = qg + (size_t)bh * 1024 * 96;
  const u16* kbase = kg + (size_t)bh * 1024 * 96;
  const u16* vbase = vg + (size_t)bh * 96 * 1024;
  s16x8 aq[3];
#pragma unroll
  for (int kc = 0; kc < 3; kc++)
    aq[kc] = *(const s16x8*)&qbase[(size_t)(q0 + l15) * 96 + kc * 32 + l4 * 8];
  float mrun[4], lrun[4];
  f32x4 accO[6] = {};
#pragma unroll
  for (int i = 0; i < 4; i++) { mrun[i] = -1e30f; lrun[i] = 0.0f; }
  __shared__ __align__(16) u16 Kl[64][104];
  __shared__ __align__(16) u16 Pl[4][16][72];
  int kkey[3], koff[3];
#pragma unroll
  for (int it = 0; it < 3; it++) {
    int c = it * 256 + tid;
    kkey[it] = c / 12; koff[it] = (c % 12) * 8;
  }
  for (int kt = 0; kt < 16; kt++) {
#pragma unroll
    for (int it = 0; it < 3; it++)
      *(uint4*)&Kl[kkey[it]][koff[it]] =
          *(const uint4*)&kbase[(size_t)(kt * 64 + kkey[it]) * 96 + koff[it]];
    __syncthreads();
    s16x8 bv[6][2];
#pragma unroll
    for (int nf = 0; nf < 6; nf++)
#pragma unroll
      for (int kc = 0; kc < 2; kc++)
        bv[nf][kc] = *(const s16x8*)&vbase[(size_t)(nf * 16 + l15) * 1024 +
                                           kt * 64 + kc * 32 + l4 * 8];
    f32x4 s4[4] = {};
    __builtin_amdgcn_s_setprio(1);
#pragma unroll
    for (int nf = 0; nf < 4; nf++)
#pragma unroll
      for (int kc = 0; kc < 3; kc++) {
        s16x8 bk = *(const s16x8*)&Kl[nf * 16 + l15][kc * 32 + l4 * 8];
        s4[nf] = MFMA16(aq[kc], bk, s4[nf]);
      }
    __builtin_amdgcn_s_setprio(0);
    float rm[4];
#pragma unroll
    for (int i = 0; i < 4; i++) {
      rm[i] = fmaxf(fmaxf(s4[0][i], s4[1][i]), fmaxf(s4[2][i], s4[3][i]));
#pragma unroll
      for (int m = 1; m < 16; m <<= 1) rm[i] = fmaxf(rm[i], __shfl_xor(rm[i], m));
    }
    bool need = (rm[0] > mrun[0]) || (rm[1] > mrun[1]) ||
                (rm[2] > mrun[2]) || (rm[3] > mrun[3]);
    if (__any(need)) {
#pragma unroll
      for (int i = 0; i < 4; i++) {
        float newm = fmaxf(mrun[i], rm[i]);
        float al = __expf(mrun[i] - newm);
        mrun[i] = newm;
        lrun[i] *= al;
#pragma unroll
        for (int nf = 0; nf < 6; nf++) accO[nf][i] *= al;
      }
    }
#pragma unroll
    for (int i = 0; i < 4; i++) {
      float ps = 0.0f;
#pragma unroll
      for (int nf = 0; nf < 4; nf++) {
        float p = __expf(s4[nf][i] - mrun[i]);
        s4[nf][i] = p;
        ps += p;
      }
#pragma unroll
      for (int m = 1; m < 16; m <<= 1) ps += __shfl_xor(ps, m);
      lrun[i] += ps;
    }
#pragma unroll
    for (int nf = 0; nf < 4; nf++)
#pragma unroll
      for (int i = 0; i < 4; i++)
        Pl[wid][l4 * 4 + i][nf * 16 + l15] = f2bf(s4[nf][i]);
    asm volatile("s_waitcnt lgkmcnt(0)" ::: "memory");
    __builtin_amdgcn_sched_barrier(0);
    __builtin_amdgcn_s_setprio(1);
#pragma unroll
    for (int kc = 0; kc < 2; kc++) {
      s16x8 ap = *(const s16x8*)&Pl[wid][l15][kc * 32 + l4 * 8];
#pragma unroll
      for (int nf = 0; nf < 6; nf++)
        accO[nf] = MFMA16(ap, bv[nf][kc], accO[nf]);
    }
    __builtin_amdgcn_s_setprio(0);
    __syncthreads();
  }
#pragma unroll
  for (int i = 0; i < 4; i++) {
    float inv = 1.0f / lrun[i];
    int tok = q0 + l4 * 4 + i;
    u16* orow = o + ((size_t)(b * 1024 + tok)) * 768 + h * 96;
#pragma unroll
    for (int nf = 0; nf < 6; nf++)
      orow[nf * 16 + l15] = f2bf(accO[nf][i] * inv);
  }
}

// ---------------------------------------------------------------------------
extern "C" void kernel_launch(void* const* d_in, const int* in_sizes, int n_in,
                              void* d_out, int out_size, void* d_ws, size_t ws_size,
                              hipStream_t stream) {
  const float* sam    = (const float*)d_in[0];
  const float* conv_w = (const float*)d_in[1];
  const float* conv_b = (const float*)d_in[2];
  const float* ln_g   = (const float*)d_in[3];
  const float* ln_b   = (const float*)d_in[4];
  const float* pos    = (const float*)d_in[5];
  const float* q_w    = (const float*)d_in[6] + (size_t)20 * 768 * 768;
  const float* kv_w   = (const float*)d_in[7] + (size_t)20 * 768 * 1536;
  const float* proj_w = (const float*)d_in[8] + (size_t)20 * 768 * 768;
  const float* proj_b = (const float*)d_in[9] + (size_t)20 * 768;

  char* ws = (char*)d_ws;
  u16* x0b    = (u16*)ws;   ws += (size_t)4096 * 768 * 2;
  u16* wqkvT  = (u16*)ws;   ws += (size_t)2304 * 768 * 2;
  u16* pwT    = (u16*)ws;   ws += (size_t)768 * 768 * 2;
  u16* cwb    = (u16*)ws;   ws += (size_t)768 * 64 * 2;
  u16* apx    = (u16*)ws;   ws += (size_t)4096 * 64 * 2;
  u16* qs     = (u16*)ws;   ws += (size_t)32 * 1024 * 96 * 2;
  u16* ks     = (u16*)ws;   ws += (size_t)32 * 1024 * 96 * 2;
  u16* vts    = (u16*)ws;   ws += (size_t)32 * 96 * 1024 * 2;
  u16* ob     = (u16*)ws;   ws += (size_t)4096 * 768 * 2;

  prep0_k<<<2444, 256, 0, stream>>>(q_w, kv_w, proj_w, wqkvT, pwT,
                                    conv_w, cwb, sam, apx);
  convln_k<<<256, 256, 0, stream>>>(apx, cwb, conv_b, ln_g, ln_b, pos, x0b);
  dim3 g1(18, 32);
  gemm128<0><<<g1, 256, 0, stream>>>(x0b, wqkvT, 4096, 2304, 768, qs, ks, vts,
                                     nullptr, nullptr, nullptr);
  attn_k<<<512, 256, 0, stream>>>(qs, ks, vts, ob);
  dim3 g2(6, 32);
  gemm128<1><<<g2, 256, 0, stream>>>(ob, pwT, 4096, 768, 768, nullptr, nullptr,
                                     nullptr, proj_b, x0b, (float*)d_out);
}